// Round 8
// baseline (276.644 us; speedup 1.0000x reference)
//
#include <hip/hip_runtime.h>

// mean( (scale*(norms - label))^2 ), scale = 5 if label==1, 3 if label==2, else 1.
// B*S = 4096*8192 = 33,554,432 elements. Memory-bound streaming reduction.
// 268 MB logical traffic @ ~6.3 TB/s achievable -> ~43 us kernel floor.
//
// R4 lesson: VGPR_Count=16 -> compiler serialized loads (only ~2 in flight),
// kernel ran at 2.7 TB/s logical. Fix: explicit 8-deep load batches per array
// (16 x 16B outstanding per thread), block-contiguous tiles, 4 accumulators.

#define BLOCK  256
#define UNROLL 8

__device__ __forceinline__ float sq_term(float n, int l) {
    // scale*norms - scale*label = scale*(norms - label)
    float s = (l == 1) ? 5.0f : ((l == 2) ? 3.0f : 1.0f);
    float d = s * (n - (float)l);
    return d * d;
}

__global__ __launch_bounds__(BLOCK) void buff_loss_kernel(
        const float* __restrict__ norms,
        const int*   __restrict__ labs,
        float*       __restrict__ out,
        int nvec,            // number of float4/int4 groups
        float inv_n) {
    const float4* __restrict__ n4 = reinterpret_cast<const float4*>(norms);
    const int4*   __restrict__ l4 = reinterpret_cast<const int4*>(labs);

    float acc0 = 0.0f, acc1 = 0.0f, acc2 = 0.0f, acc3 = 0.0f;

    const int chunk   = BLOCK * UNROLL;               // float4s per block-tile
    const int gstride = gridDim.x * chunk;
    int base = blockIdx.x * chunk + threadIdx.x;

    // Main loop: each thread loads 8 float4 + 8 int4 as independent batches
    // (all 16 loads in flight before first use), block-contiguous addresses.
    for (; base + (UNROLL - 1) * BLOCK < nvec; base += gstride) {
        float4 nb[UNROLL];
        int4   lb[UNROLL];
        #pragma unroll
        for (int k = 0; k < UNROLL; ++k) nb[k] = n4[base + k * BLOCK];
        #pragma unroll
        for (int k = 0; k < UNROLL; ++k) lb[k] = l4[base + k * BLOCK];
        #pragma unroll
        for (int k = 0; k < UNROLL; ++k) {
            acc0 += sq_term(nb[k].x, lb[k].x);
            acc1 += sq_term(nb[k].y, lb[k].y);
            acc2 += sq_term(nb[k].z, lb[k].z);
            acc3 += sq_term(nb[k].w, lb[k].w);
        }
    }
    // Tail (never taken for 4096x8192, but keeps the kernel shape-generic).
    for (; base < nvec; base += BLOCK) {
        float4 n = n4[base];
        int4   l = l4[base];
        acc0 += sq_term(n.x, l.x);
        acc1 += sq_term(n.y, l.y);
        acc2 += sq_term(n.z, l.z);
        acc3 += sq_term(n.w, l.w);
    }

    float acc = (acc0 + acc1) + (acc2 + acc3);

    // wave64 shuffle reduction
    #pragma unroll
    for (int off = 32; off > 0; off >>= 1)
        acc += __shfl_down(acc, off, 64);

    __shared__ float smem[BLOCK / 64];
    int lane = threadIdx.x & 63;
    int wid  = threadIdx.x >> 6;
    if (lane == 0) smem[wid] = acc;
    __syncthreads();

    if (threadIdx.x == 0) {
        float t = (smem[0] + smem[1]) + (smem[2] + smem[3]);
        atomicAdd(out, t * inv_n);
    }
}

extern "C" void kernel_launch(void* const* d_in, const int* in_sizes, int n_in,
                              void* d_out, int out_size, void* d_ws, size_t ws_size,
                              hipStream_t stream) {
    const float* norms = (const float*)d_in[0];
    const int*   labs  = (const int*)d_in[1];
    float*       out   = (float*)d_out;

    int n    = in_sizes[0];          // 33,554,432 (divisible by 4)
    int nvec = n >> 2;               // float4 groups = 8,388,608
    float inv_n = 1.0f / (float)n;

    // d_out is re-poisoned to 0xAA before every timed call — zero it first.
    hipMemsetAsync(d_out, 0, sizeof(float), stream);

    const int chunk = BLOCK * UNROLL;                 // 2048 float4s per block
    int grid = (nvec + chunk - 1) / chunk;            // 4096 blocks for this shape
    if (grid > 16384) grid = 16384;
    if (grid < 1) grid = 1;

    buff_loss_kernel<<<grid, BLOCK, 0, stream>>>(norms, labs, out, nvec, inv_n);
}